// Round 7
// baseline (219.725 us; speedup 1.0000x reference)
//
#include <hip/hip_runtime.h>
#include <hip/hip_bf16.h>
#include <stdint.h>

#define B_ 2
#define T_ 2048
#define C_ 1024
#define H_ 16
#define D_ 64

typedef __attribute__((ext_vector_type(8))) short short8;
typedef __attribute__((ext_vector_type(4))) float floatx4;

__device__ __forceinline__ float bf2f(uint16_t b) {
    return __uint_as_float(((uint32_t)b) << 16);
}
__device__ __forceinline__ uint16_t f2b(float f) {
    __hip_bfloat16 h = __float2bfloat16(f);  // RNE
    return *(uint16_t*)&h;
}
// 2^x via v_exp_f32 (gfx9 transcendentals are HW-interlocked; reg-only asm)
__device__ __forceinline__ float exp2v(float x) {
    float r;
    asm("v_exp_f32 %0, %1" : "=v"(r) : "v"(x));
    return r;
}
// pack 2 f32 -> 2 bf16 (RNE), lo first
__device__ __forceinline__ uint32_t cvtpk(float lo, float hi) {
    uint32_t r;
    asm("v_cvt_pk_bf16_f32 %0, %1, %2" : "=v"(r) : "v"(lo), "v"(hi));
    return r;
}
__device__ __forceinline__ void glds16(const uint16_t* g, uint16_t* l) {
    __builtin_amdgcn_global_load_lds(
        (const __attribute__((address_space(1))) uint32_t*)g,
        (__attribute__((address_space(3))) uint32_t*)l, 16, 0, 0);
}

// ---- fused prep: canon x (fp32->bf16) + both weight transposes ------------
// blocks [0,4096): canon; [4096,7168): w_qkv transpose; [7168,8192): w_proj.
__global__ void prep(const float* __restrict__ x, uint16_t* __restrict__ x_c,
                     const float* __restrict__ w_qkv, uint16_t* __restrict__ wt_qkv,
                     const float* __restrict__ w_proj, uint16_t* __restrict__ wt_proj) {
    __shared__ uint16_t tile[32][33];
    int id = blockIdx.x;
    int tid = threadIdx.x;
    if (id < 4096) {
        int i = (id * 256 + tid) * 4;
        float4 v = *(const float4*)(x + i);
        x_c[i + 0] = f2b(v.x);
        x_c[i + 1] = f2b(v.y);
        x_c[i + 2] = f2b(v.z);
        x_c[i + 3] = f2b(v.w);
        return;
    }
    const float* in;
    uint16_t* out;
    int R, W, bx, by;
    if (id < 7168) {
        int tb = id - 4096;
        in = w_qkv; out = wt_qkv; R = 1024; W = 3072;
        bx = tb % 96; by = tb / 96;
    } else {
        int tb = id - 7168;
        in = w_proj; out = wt_proj; R = 1024; W = 1024;
        bx = tb & 31; by = tb >> 5;
    }
    int tx = tid & 31, ty = tid >> 5;
    int c0 = bx * 32, r0 = by * 32;
    #pragma unroll
    for (int i = 0; i < 32; i += 8)
        tile[ty + i][tx] = f2b(in[(size_t)(r0 + ty + i) * W + (c0 + tx)]);
    __syncthreads();
    #pragma unroll
    for (int i = 0; i < 32; i += 8)
        out[(size_t)(c0 + ty + i) * R + (r0 + tx)] = tile[tx][ty + i];
}

// ------- GEMM: C[M,N] = A[M,K] @ Bt[N,K]^T ; bf16 in, fp32 acc -------------
// Counted-vmcnt pipeline (T3+T4): BK=32, THREE LDS buffers, depth-2
// global_load_lds prefetch; never drain vmcnt to 0 in the main loop (m218).
// XOR slot swizzle with pre-swizzled global source. Grid 1D, bijective XCD
// swizzle (nwg % 8 == 0), A-panel-major.
// BN template: 128 (per-wave 64x64, 4 loads/tile) or 64 (per-wave 64x32,
// 3 loads/tile) -- BN=64 doubles the proj grid to 2 blocks/CU.
template <bool OUT_F32, int BN>
__global__ __launch_bounds__(256, 3)
void gemm_bt(const uint16_t* __restrict__ A, const uint16_t* __restrict__ Bt,
             void* __restrict__ Cv, int M, int N, int K) {
    constexpr int NJ = BN / 32;           // per-wave 16-col frags
    constexpr int BUFB = BN * 32;         // u16 per B buffer
    __shared__ uint16_t As[3][128][32];
    __shared__ uint16_t Bs[3][BN][32];
    int tid = threadIdx.x;
    int w = tid >> 6, lane = tid & 63;
    int quad = lane >> 4, l16 = lane & 15;
    int wr = (w >> 1) * 64, wc = (w & 1) * (BN / 2);

    int nwg = gridDim.x;
    int wg = (blockIdx.x & 7) * (nwg >> 3) + (blockIdx.x >> 3);
    int nby = N / BN;
    int row0 = (wg / nby) * 128;
    int col0 = (wg % nby) * BN;

    // A staging: wave w rows w*32+(lane>>2) and +16; phys slot lane&3,
    // pre-swizzled source k-slot (lane&3)^(row&3).
    int sr = w * 32 + (lane >> 2);
    int gscA = ((lane & 3) ^ ((lane >> 2) & 3)) * 8;
    uint16_t* lA0 = &As[0][sr][(lane & 3) * 8];
    const uint16_t* gA = A + (size_t)(row0 + sr) * K + gscA;
    // B staging: BN=128 -> rows sr, sr+16 (2 loads); BN=64 -> row tid>>2 (1).
    int srB = (BN == 128) ? sr : (tid >> 2);
    int gscB = ((lane & 3) ^ (srB & 3)) * 8;
    uint16_t* lB0 = &Bs[0][srB][(lane & 3) * 8];
    const uint16_t* gB = Bt + (size_t)(col0 + srB) * K + gscB;

    floatx4 acc[4][NJ];
    #pragma unroll
    for (int i = 0; i < 4; i++)
        #pragma unroll
        for (int j = 0; j < NJ; j++)
            acc[i][j] = (floatx4){0.f, 0.f, 0.f, 0.f};

#define STAGE3_(bs_, t_)                                                    \
    {                                                                       \
        const uint16_t* ga_ = gA + (size_t)(t_) * 32;                       \
        const uint16_t* gb_ = gB + (size_t)(t_) * 32;                       \
        uint16_t* la_ = lA0 + (bs_) * 4096;                                 \
        uint16_t* lb_ = lB0 + (bs_) * BUFB;                                 \
        glds16(ga_, la_);                                                   \
        glds16(ga_ + 16 * K, la_ + 512);                                    \
        glds16(gb_, lb_);                                                   \
        if constexpr (BN == 128) glds16(gb_ + 16 * K, lb_ + 512);           \
    }

    int NT = K >> 5;                 // K=1024 -> 32 tiles
    STAGE3_(0, 0);
    STAGE3_(1, 1);
    if constexpr (BN == 128)
        asm volatile("s_waitcnt vmcnt(4)" ::: "memory");   // tile 0 resident
    else
        asm volatile("s_waitcnt vmcnt(3)" ::: "memory");
    __builtin_amdgcn_s_barrier();

    const uint16_t* Ab = &As[0][0][0];
    const uint16_t* Bb = &Bs[0][0][0];
    int s = (quad ^ (l16 & 3)) * 8;  // swizzled read slot (loop-invariant)
    int bc = 0, bs = 2;
    for (int t = 0; t < NT; ++t) {
        if (t + 2 < NT) STAGE3_(bs, t + 2);
        __builtin_amdgcn_sched_barrier(0);   // pin stage issue before compute
        const uint16_t* Ac = Ab + bc * 4096;
        const uint16_t* Bc = Bb + bc * BUFB;
        short8 af[4], bfr[NJ];
        #pragma unroll
        for (int i = 0; i < 4; i++)
            af[i] = *(const short8*)&Ac[(wr + i * 16 + l16) * 32 + s];
        #pragma unroll
        for (int j = 0; j < NJ; j++)
            bfr[j] = *(const short8*)&Bc[(wc + j * 16 + l16) * 32 + s];
        #pragma unroll
        for (int i = 0; i < 4; i++)
            #pragma unroll
            for (int j = 0; j < NJ; j++)
                acc[i][j] = __builtin_amdgcn_mfma_f32_16x16x32_bf16(
                    af[i], bfr[j], acc[i][j], 0, 0, 0);
        if (t + 2 < NT) {
            if constexpr (BN == 128)
                asm volatile("s_waitcnt vmcnt(4)" ::: "memory");  // t+1 ready
            else
                asm volatile("s_waitcnt vmcnt(3)" ::: "memory");
        } else {
            asm volatile("s_waitcnt vmcnt(0)" ::: "memory");      // tail drain
        }
        __builtin_amdgcn_s_barrier();
        bc = (bc == 2) ? 0 : bc + 1;
        bs = (bs == 2) ? 0 : bs + 1;
    }
#undef STAGE3_

    #pragma unroll
    for (int i = 0; i < 4; i++) {
        #pragma unroll
        for (int j = 0; j < NJ; j++) {
            int rbase = row0 + wr + i * 16 + quad * 4;
            int cg = col0 + wc + j * 16 + l16;
            #pragma unroll
            for (int r = 0; r < 4; r++) {
                if (OUT_F32)
                    ((float*)Cv)[(size_t)(rbase + r) * N + cg] = acc[i][j][r];
                else
                    ((uint16_t*)Cv)[(size_t)(rbase + r) * N + cg] = f2b(acc[i][j][r]);
            }
        }
    }
}

// ---------------- MFMA flash attention with sink ---------------------------
// STRIP-PER-BLOCK (r6) + K-FROM-GLOBAL: K fragments are contiguous 16B/lane
// in row-major qkv, so each wave loads them global->VGPR directly (8 x
// dwordx4/tile, L1/L2-served -- all 4 waves read the same 8KB). This deletes
// the Ks LDS buffer, its staging writes and its 32KB/block-tile of ds_reads
// + conflicts: LDS traffic 96->56 KB per block-tile, moved onto the idle
// TA/L2 pipe (r6 showed DS pipe saturated: occupancy +40% -> 0 gain).
// Only V (needs transpose) is staged; LDS 27.6 KB -> 4 blocks/CU.
// log2-space softmax, defer-max (T13, THR=8), cvt_pk P-packing.
__global__ __launch_bounds__(256, 4)
void attn_mfma(const uint16_t* __restrict__ qkv,
               const float* __restrict__ sink,
               uint16_t* __restrict__ y) {
    __shared__ uint16_t Vt[2][64][72];   // [buf][d][key]   18432 B (swizzled)
    __shared__ uint16_t Pl[4][16][72];   // per-wave [q][key] 9216 B

    int tid = threadIdx.x;
    int w = tid >> 6, lane = tid & 63;
    int quad = lane >> 4, l16 = lane & 15;

    int id = blockIdx.x;
    int strip = 31 - (id >> 5);         // longest first
    int bh = id & 31;
    int b = bh >> 4, h = bh & 15;
    int q0 = strip * 64 + w * 16;       // this wave's 16 q rows
    int ktiles = strip + 1;

    const uint16_t* qkv_b = qkv + (size_t)b * T_ * 3072;

    // ---- Q fragments: 2 kd, pre-scaled by log2(e)/8 ----
    const float QSC = 0.125f * 1.44269504f;
    short8 qf[2];
    {
        int qrow = q0 + l16;
        #pragma unroll
        for (int kd = 0; kd < 2; kd++) {
            uint4 raw = *(const uint4*)(qkv_b + (size_t)qrow * 3072 + h * 64 +
                                        kd * 32 + quad * 8);
            const uint16_t* rp = (const uint16_t*)&raw;
            short8 f;
            #pragma unroll
            for (int j = 0; j < 8; j++)
                f[j] = (short)f2b(bf2f(rp[j]) * QSC);
            qf[kd] = f;
        }
    }

    float m_s = sink[h] * 1.44269504f;   // log2 space
    float l_s = 1.0f;
    floatx4 acc_o[4];
    #pragma unroll
    for (int dt = 0; dt < 4; dt++)
        acc_o[dt] = (floatx4){0.f, 0.f, 0.f, 0.f};

    // ---- per-lane K fragment base: token l16, dim quad*8 ----
    const uint16_t* kfp = qkv_b + 1024 + h * 64 + (size_t)l16 * 3072 + quad * 8;

    // ---- V staging map: thread (t2,dg): key rows 2t2,2t2+1, dims dg*8..+7 --
    int t2 = tid >> 3;
    int dg = tid & 7;
    const uint16_t* vgp = qkv_b + 2048 + h * 64 + (size_t)(2 * t2) * 3072 + dg * 8;
    int vcw = 2 * (t2 ^ (4 * dg));   // swizzled u16 col for V^T key-pair store

    uint4 vr0 = *(const uint4*)(vgp);
    uint4 vr1 = *(const uint4*)(vgp + 3072);
    // store tile 0 -> buf 0
    {
        const uint16_t* a0 = (const uint16_t*)&vr0;
        const uint16_t* a1 = (const uint16_t*)&vr1;
        #pragma unroll
        for (int j = 0; j < 8; j++)
            *(uint32_t*)&Vt[0][dg * 8 + j][vcw] =
                (uint32_t)a0[j] | ((uint32_t)a1[j] << 16);
    }
    if (ktiles > 1) {   // preload tile 1
        vr0 = *(const uint4*)(vgp + 64 * 3072);
        vr1 = *(const uint4*)(vgp + 64 * 3072 + 3072);
    }
    __syncthreads();

    for (int kt = 0; kt < ktiles; kt++) {
        int cur = kt & 1;
        // ---- K fragments straight from global (L1/L2-hit for waves 1..3) --
        short8 kf[4][2];
        {
            const uint16_t* kp0 = kfp + (size_t)(kt * 64) * 3072;
            #pragma unroll
            for (int rt = 0; rt < 4; rt++) {
                kf[rt][0] = *(const short8*)(kp0 + (size_t)(rt * 16) * 3072);
                kf[rt][1] = *(const short8*)(kp0 + (size_t)(rt * 16) * 3072 + 32);
            }
        }
        // ---- store prefetched V tile kt+1 into the other buffer ----
        if (kt + 1 < ktiles) {
            const uint16_t* a0 = (const uint16_t*)&vr0;
            const uint16_t* a1 = (const uint16_t*)&vr1;
            #pragma unroll
            for (int j = 0; j < 8; j++)
                *(uint32_t*)&Vt[cur ^ 1][dg * 8 + j][vcw] =
                    (uint32_t)a0[j] | ((uint32_t)a1[j] << 16);
        }
        // ---- issue V prefetch of tile kt+2 (lands during this iter) ----
        if (kt + 2 < ktiles) {
            size_t off = (size_t)(kt + 2) * 64 * 3072;
            vr0 = *(const uint4*)(vgp + off);
            vr1 = *(const uint4*)(vgp + off + 3072);
        }
        // ---- V fragments from LDS ----
        short8 vf[2][4];
        #pragma unroll
        for (int kb = 0; kb < 2; kb++)
            #pragma unroll
            for (int dt = 0; dt < 4; dt++) {
                int d = dt * 16 + l16;
                int col = 2 * (((kb * 16) + quad * 4) ^ (4 * (d >> 3)));
                vf[kb][dt] = *(const short8*)&Vt[cur][d][col];
            }
        // ---- S^T = K * Q^T : key = rt*16+quad*4+r, q = l16 ----
        floatx4 acc_s[4];
        #pragma unroll
        for (int rt = 0; rt < 4; rt++)
            acc_s[rt] = (floatx4){0.f, 0.f, 0.f, 0.f};
        #pragma unroll
        for (int rt = 0; rt < 4; rt++) {
            acc_s[rt] = __builtin_amdgcn_mfma_f32_16x16x32_bf16(
                kf[rt][0], qf[0], acc_s[rt], 0, 0, 0);
            acc_s[rt] = __builtin_amdgcn_mfma_f32_16x16x32_bf16(
                kf[rt][1], qf[1], acc_s[rt], 0, 0, 0);
        }
        // ---- causal mask: only the diagonal tile ----
        if (kt == strip) {
            int qg = q0 + l16;
            #pragma unroll
            for (int rt = 0; rt < 4; rt++) {
                int kg = kt * 64 + rt * 16 + quad * 4;
                #pragma unroll
                for (int r = 0; r < 4; r++)
                    if (kg + r > qg) acc_s[rt][r] = -1e30f;
            }
        }
        // ---- online softmax in log2 space (q = l16) ----
        float mx = -1e30f;
        #pragma unroll
        for (int rt = 0; rt < 4; rt++)
            #pragma unroll
            for (int r = 0; r < 4; r++) mx = fmaxf(mx, acc_s[rt][r]);
        mx = fmaxf(mx, __shfl_xor(mx, 16));
        mx = fmaxf(mx, __shfl_xor(mx, 32));
        float mold = m_s;
        // T13 defer-max: only rescale when tile max exceeds m by >8
        if (!__all(mx <= mold + 8.0f)) {
            float mnew = fmaxf(mold, mx);
            float alpha = exp2v(mold - mnew);
            m_s = mnew;
            l_s *= alpha;
            #pragma unroll
            for (int r = 0; r < 4; r++) {
                float ar = __shfl(alpha, (lane & 48) | (quad * 4 + r));
                #pragma unroll
                for (int dt = 0; dt < 4; dt++) acc_o[dt][r] *= ar;
            }
        }
        float mcur = m_s;
        float psum = 0.f;
        #pragma unroll
        for (int rt = 0; rt < 4; rt++) {
            float p0 = exp2v(acc_s[rt][0] - mcur);
            float p1 = exp2v(acc_s[rt][1] - mcur);
            float p2 = exp2v(acc_s[rt][2] - mcur);
            float p3 = exp2v(acc_s[rt][3] - mcur);
            psum += (p0 + p1) + (p2 + p3);
            uint2 pk;
            pk.x = cvtpk(p0, p1);
            pk.y = cvtpk(p2, p3);
            *(uint2*)&Pl[w][l16][rt * 16 + quad * 4] = pk;
        }
        psum += __shfl_xor(psum, 16);
        psum += __shfl_xor(psum, 32);
        l_s += psum;
        // ---- O += P * V ----
        #pragma unroll
        for (int kb = 0; kb < 2; kb++) {
            short8 pf = *(const short8*)&Pl[w][l16][kb * 32 + quad * 8];
            #pragma unroll
            for (int dt = 0; dt < 4; dt++)
                acc_o[dt] = __builtin_amdgcn_mfma_f32_16x16x32_bf16(
                    pf, vf[kb][dt], acc_o[dt], 0, 0, 0);
        }
        __syncthreads();
    }

    // ---- epilogue: normalize by l (per-q via in-quad shuffle), store bf16 --
    #pragma unroll
    for (int r = 0; r < 4; r++) {
        float lr = __shfl(l_s, (lane & 48) | (quad * 4 + r));
        float inv = 1.0f / lr;
        int qg = q0 + quad * 4 + r;
        uint16_t* yp = y + (size_t)(b * T_ + qg) * 1024 + h * 64;
        #pragma unroll
        for (int dt = 0; dt < 4; dt++)
            yp[dt * 16 + l16] = f2b(acc_o[dt][r] * inv);
    }
}

extern "C" void kernel_launch(void* const* d_in, const int* in_sizes, int n_in,
                              void* d_out, int out_size, void* d_ws, size_t ws_size,
                              hipStream_t stream) {
    const float* x      = (const float*)d_in[0];  // [B,T,C] fp32
    const float* w_qkv  = (const float*)d_in[1];  // [C, 3HD] fp32
    const float* w_proj = (const float*)d_in[2];  // [HD, C] fp32
    const float* sink   = (const float*)d_in[3];  // [H] fp32
    float* out          = (float*)d_out;          // [B,T,C] fp32

    char* ws = (char*)d_ws;
    uint16_t* wt_qkv  = (uint16_t*)ws;                       // [3072,1024] 6.29 MB
    uint16_t* wt_proj = (uint16_t*)(ws + 6291456);           // [1024,1024] 2.10 MB
    uint16_t* x_c     = (uint16_t*)(ws + 8388608);           // [4096,1024] 8.39 MB
    uint16_t* qkv     = (uint16_t*)(ws + 16777216);          // [4096,3072] 25.17 MB
    uint16_t* yb      = (uint16_t*)(ws + 41943040);          // [4096,1024] 8.39 MB

    // fused prep: canon + both transposes in ONE dispatch
    prep<<<dim3(8192), 256, 0, stream>>>(x, x_c, w_qkv, wt_qkv, w_proj, wt_proj);

    // 1D grids, nwg % 8 == 0 (bijective XCD swizzle inside)
    gemm_bt<false, 128><<<dim3(768), 256, 0, stream>>>(
        x_c, wt_qkv, qkv, 4096, 3072, 1024);

    // strip-per-block grid: id = (31-strip)*32 + bh (longest first; id%8=bh%8)
    attn_mfma<<<dim3(32 * 32), 256, 0, stream>>>(qkv, sink, yb);

    // proj: 128x64 tiles -> 512 blocks = 2 blocks/CU (was 256 = 1/CU)
    gemm_bt<true, 64><<<dim3(512), 256, 0, stream>>>(
        yb, wt_proj, out, 4096, 1024, 1024);
}

// Round 9
// 195.113 us; speedup vs baseline: 1.1261x; 1.1261x over previous
//
#include <hip/hip_runtime.h>
#include <hip/hip_bf16.h>
#include <stdint.h>

#define B_ 2
#define T_ 2048
#define C_ 1024
#define H_ 16
#define D_ 64

typedef __attribute__((ext_vector_type(8))) short short8;
typedef __attribute__((ext_vector_type(4))) float floatx4;
typedef __attribute__((ext_vector_type(16))) float floatx16;

__device__ __forceinline__ float bf2f(uint16_t b) {
    return __uint_as_float(((uint32_t)b) << 16);
}
__device__ __forceinline__ uint16_t f2b(float f) {
    __hip_bfloat16 h = __float2bfloat16(f);  // RNE
    return *(uint16_t*)&h;
}
// 2^x via v_exp_f32 (gfx9 transcendentals are HW-interlocked; reg-only asm)
__device__ __forceinline__ float exp2v(float x) {
    float r;
    asm("v_exp_f32 %0, %1" : "=v"(r) : "v"(x));
    return r;
}
// pack 2 f32 -> 2 bf16 (RNE), lo first
__device__ __forceinline__ uint32_t cvtpk(float lo, float hi) {
    uint32_t r;
    asm("v_cvt_pk_bf16_f32 %0, %1, %2" : "=v"(r) : "v"(lo), "v"(hi));
    return r;
}
__device__ __forceinline__ void glds16(const uint16_t* g, uint16_t* l) {
    __builtin_amdgcn_global_load_lds(
        (const __attribute__((address_space(1))) uint32_t*)g,
        (__attribute__((address_space(3))) uint32_t*)l, 16, 0, 0);
}

// ---- fused prep: canon x (fp32->bf16) + both weight transposes ------------
// blocks [0,4096): canon; [4096,7168): w_qkv transpose; [7168,8192): w_proj.
__global__ void prep(const float* __restrict__ x, uint16_t* __restrict__ x_c,
                     const float* __restrict__ w_qkv, uint16_t* __restrict__ wt_qkv,
                     const float* __restrict__ w_proj, uint16_t* __restrict__ wt_proj) {
    __shared__ uint16_t tile[32][33];
    int id = blockIdx.x;
    int tid = threadIdx.x;
    if (id < 4096) {
        int i = (id * 256 + tid) * 4;
        float4 v = *(const float4*)(x + i);
        x_c[i + 0] = f2b(v.x);
        x_c[i + 1] = f2b(v.y);
        x_c[i + 2] = f2b(v.z);
        x_c[i + 3] = f2b(v.w);
        return;
    }
    const float* in;
    uint16_t* out;
    int R, W, bx, by;
    if (id < 7168) {
        int tb = id - 4096;
        in = w_qkv; out = wt_qkv; R = 1024; W = 3072;
        bx = tb % 96; by = tb / 96;
    } else {
        int tb = id - 7168;
        in = w_proj; out = wt_proj; R = 1024; W = 1024;
        bx = tb & 31; by = tb >> 5;
    }
    int tx = tid & 31, ty = tid >> 5;
    int c0 = bx * 32, r0 = by * 32;
    #pragma unroll
    for (int i = 0; i < 32; i += 8)
        tile[ty + i][tx] = f2b(in[(size_t)(r0 + ty + i) * W + (c0 + tx)]);
    __syncthreads();
    #pragma unroll
    for (int i = 0; i < 32; i += 8)
        out[(size_t)(c0 + ty + i) * R + (r0 + tx)] = tile[tx][ty + i];
}

// ------- GEMM: C[M,N] = A[M,K] @ Bt[N,K]^T ; bf16 in, fp32 acc -------------
// Counted-vmcnt pipeline (T3+T4): BK=32, THREE LDS buffers, depth-2
// global_load_lds prefetch; never drain vmcnt to 0 in the main loop (m218).
// XOR slot swizzle with pre-swizzled global source. Grid 1D, bijective XCD
// swizzle (nwg % 8 == 0), A-panel-major.
template <bool OUT_F32, int BN>
__global__ __launch_bounds__(256, 3)
void gemm_bt(const uint16_t* __restrict__ A, const uint16_t* __restrict__ Bt,
             void* __restrict__ Cv, int M, int N, int K) {
    constexpr int NJ = BN / 32;           // per-wave 16-col frags
    constexpr int BUFB = BN * 32;         // u16 per B buffer
    __shared__ uint16_t As[3][128][32];
    __shared__ uint16_t Bs[3][BN][32];
    int tid = threadIdx.x;
    int w = tid >> 6, lane = tid & 63;
    int quad = lane >> 4, l16 = lane & 15;
    int wr = (w >> 1) * 64, wc = (w & 1) * (BN / 2);

    int nwg = gridDim.x;
    int wg = (blockIdx.x & 7) * (nwg >> 3) + (blockIdx.x >> 3);
    int nby = N / BN;
    int row0 = (wg / nby) * 128;
    int col0 = (wg % nby) * BN;

    int sr = w * 32 + (lane >> 2);
    int gscA = ((lane & 3) ^ ((lane >> 2) & 3)) * 8;
    uint16_t* lA0 = &As[0][sr][(lane & 3) * 8];
    const uint16_t* gA = A + (size_t)(row0 + sr) * K + gscA;
    int srB = (BN == 128) ? sr : (tid >> 2);
    int gscB = ((lane & 3) ^ (srB & 3)) * 8;
    uint16_t* lB0 = &Bs[0][srB][(lane & 3) * 8];
    const uint16_t* gB = Bt + (size_t)(col0 + srB) * K + gscB;

    floatx4 acc[4][NJ];
    #pragma unroll
    for (int i = 0; i < 4; i++)
        #pragma unroll
        for (int j = 0; j < NJ; j++)
            acc[i][j] = (floatx4){0.f, 0.f, 0.f, 0.f};

#define STAGE3_(bs_, t_)                                                    \
    {                                                                       \
        const uint16_t* ga_ = gA + (size_t)(t_) * 32;                       \
        const uint16_t* gb_ = gB + (size_t)(t_) * 32;                       \
        uint16_t* la_ = lA0 + (bs_) * 4096;                                 \
        uint16_t* lb_ = lB0 + (bs_) * BUFB;                                 \
        glds16(ga_, la_);                                                   \
        glds16(ga_ + 16 * K, la_ + 512);                                    \
        glds16(gb_, lb_);                                                   \
        if constexpr (BN == 128) glds16(gb_ + 16 * K, lb_ + 512);           \
    }

    int NT = K >> 5;                 // K=1024 -> 32 tiles
    STAGE3_(0, 0);
    STAGE3_(1, 1);
    if constexpr (BN == 128)
        asm volatile("s_waitcnt vmcnt(4)" ::: "memory");   // tile 0 resident
    else
        asm volatile("s_waitcnt vmcnt(3)" ::: "memory");
    __builtin_amdgcn_s_barrier();

    const uint16_t* Ab = &As[0][0][0];
    const uint16_t* Bb = &Bs[0][0][0];
    int s = (quad ^ (l16 & 3)) * 8;  // swizzled read slot (loop-invariant)
    int bc = 0, bs = 2;
    for (int t = 0; t < NT; ++t) {
        if (t + 2 < NT) STAGE3_(bs, t + 2);
        __builtin_amdgcn_sched_barrier(0);   // pin stage issue before compute
        const uint16_t* Ac = Ab + bc * 4096;
        const uint16_t* Bc = Bb + bc * BUFB;
        short8 af[4], bfr[NJ];
        #pragma unroll
        for (int i = 0; i < 4; i++)
            af[i] = *(const short8*)&Ac[(wr + i * 16 + l16) * 32 + s];
        #pragma unroll
        for (int j = 0; j < NJ; j++)
            bfr[j] = *(const short8*)&Bc[(wc + j * 16 + l16) * 32 + s];
        #pragma unroll
        for (int i = 0; i < 4; i++)
            #pragma unroll
            for (int j = 0; j < NJ; j++)
                acc[i][j] = __builtin_amdgcn_mfma_f32_16x16x32_bf16(
                    af[i], bfr[j], acc[i][j], 0, 0, 0);
        if (t + 2 < NT) {
            if constexpr (BN == 128)
                asm volatile("s_waitcnt vmcnt(4)" ::: "memory");  // t+1 ready
            else
                asm volatile("s_waitcnt vmcnt(3)" ::: "memory");
        } else {
            asm volatile("s_waitcnt vmcnt(0)" ::: "memory");      // tail drain
        }
        __builtin_amdgcn_s_barrier();
        bc = (bc == 2) ? 0 : bc + 1;
        bs = (bs == 2) ? 0 : bs + 1;
    }
#undef STAGE3_

    #pragma unroll
    for (int i = 0; i < 4; i++) {
        #pragma unroll
        for (int j = 0; j < NJ; j++) {
            int rbase = row0 + wr + i * 16 + quad * 4;
            int cg = col0 + wc + j * 16 + l16;
            #pragma unroll
            for (int r = 0; r < 4; r++) {
                if (OUT_F32)
                    ((float*)Cv)[(size_t)(rbase + r) * N + cg] = acc[i][j][r];
                else
                    ((uint16_t*)Cv)[(size_t)(rbase + r) * N + cg] = f2b(acc[i][j][r]);
            }
        }
    }
}

// ---------------- MFMA flash attention, 32x32 in-register softmax ----------
// Strip-per-block (1024 blocks), 128 threads = 2 waves x 32 q-rows each.
// Swapped QK^T via mfma_32x32x16(K, Q^T): C/D col=lane&31=q, so each lane
// holds 32 of its q-row's 64 keys in regs (partner lane has the rest):
// softmax = in-lane chains + 1 shfl_xor(32). P->bf16 B-frags in-register:
// 16 v_cvt_pk_bf16_f32 + 8 v_permlane32_swap_b32 (T12) -- NO P LDS trip.
// permlane32_swap(vdst,vsrc): vdst[l>=32] <-> vsrc[l<32]. With (X, Z):
// hi=0 keeps X=(k0,k1), gains Z=partner X=(k4,k5); hi=1 gains X=partner
// Z=(k8,k9), keeps Z=(k12,k13) -> words 0..3 = keys base..base+7 per lane.
// PV as O^T = V^T * P^T => alpha/normalize are per-lane scalars (no shfl).
// K staged plain [64][72]; V transposed [d][key] with col-group swizzle
// kg^(2*(d>>3)). LDS 36.9 KB -> 4 blocks/CU. log2 softmax + defer-max (T13).
__global__ __launch_bounds__(128, 2)
void attn_mfma(const uint16_t* __restrict__ qkv,
               const float* __restrict__ sink,
               uint16_t* __restrict__ y) {
    __shared__ uint16_t Ks[2][64][72];   // [buf][key][d]   18432 B
    __shared__ uint16_t Vt[2][64][72];   // [buf][d][key-swz] 18432 B

    int tid = threadIdx.x;
    int w = tid >> 6, lane = tid & 63;
    int l = lane & 31, hi = lane >> 5;

    int id = blockIdx.x;
    int strip = 31 - (id >> 5);         // longest first
    int bh = id & 31;
    int b = bh >> 4, h = bh & 15;
    int q0w = strip * 64 + w * 32;      // this wave's 32 q rows
    int ktiles = strip + 1;

    const uint16_t* qkv_b = qkv + (size_t)b * T_ * 3072;

    // ---- Q fragments (B-operand): col q = q0w+l, k-slice kk*16+hi*8 ----
    const float QSC = 0.125f * 1.44269504f;
    short8 qf[4];
    {
        const uint16_t* qp = qkv_b + (size_t)(q0w + l) * 3072 + h * 64 + hi * 8;
        #pragma unroll
        for (int kk = 0; kk < 4; kk++) {
            uint4 raw = *(const uint4*)(qp + kk * 16);
            const uint16_t* rp = (const uint16_t*)&raw;
            short8 f;
            #pragma unroll
            for (int j = 0; j < 8; j++)
                f[j] = (short)f2b(bf2f(rp[j]) * QSC);
            qf[kk] = f;
        }
    }

    float m_s = sink[h] * 1.44269504f;   // log2 space
    float l_s = 1.0f;
    floatx16 acc_o[2];
    acc_o[0] = (floatx16)0.0f;
    acc_o[1] = (floatx16)0.0f;

    // ---- staging map: thread (g4,dg): K rows 4g4..+3 cols dg*8;
    //      V keys 4g4..+3 at rows dg*8..+7, swizzled col 4*((g4^(2dg))&15) --
    int g4 = tid >> 3;                  // 0..15
    int dg = tid & 7;                   // 0..7
    const uint16_t* gkp = qkv_b + 1024 + h * 64 + (size_t)(4 * g4) * 3072 + dg * 8;
    const uint16_t* gvp = gkp + 1024;
    int vcol = 4 * ((g4 ^ (2 * dg)) & 15);

    uint4 kq[4], vq[4];

#define STOREV_(buf_)                                                         \
    {                                                                         \
        _Pragma("unroll") for (int j = 0; j < 8; j++) {                       \
            uint2 pr;                                                         \
            pr.x = (uint32_t)((const uint16_t*)&vq[0])[j] |                   \
                   ((uint32_t)((const uint16_t*)&vq[1])[j] << 16);            \
            pr.y = (uint32_t)((const uint16_t*)&vq[2])[j] |                   \
                   ((uint32_t)((const uint16_t*)&vq[3])[j] << 16);            \
            *(uint2*)&Vt[buf_][dg * 8 + j][vcol] = pr;                        \
        }                                                                     \
    }

    // tile 0 -> buf 0
    #pragma unroll
    for (int i = 0; i < 4; i++) {
        uint4 kv = *(const uint4*)(gkp + (size_t)i * 3072);
        *(uint4*)&Ks[0][4 * g4 + i][dg * 8] = kv;
        vq[i] = *(const uint4*)(gvp + (size_t)i * 3072);
    }
    STOREV_(0);
    if (ktiles > 1) {   // prefetch tile 1 into regs
        #pragma unroll
        for (int i = 0; i < 4; i++) {
            kq[i] = *(const uint4*)(gkp + 64 * 3072 + (size_t)i * 3072);
            vq[i] = *(const uint4*)(gvp + 64 * 3072 + (size_t)i * 3072);
        }
    }
    __syncthreads();

    for (int kt = 0; kt < ktiles; kt++) {
        int cur = kt & 1;
        // ---- store prefetched tile kt+1 into the other buffer ----
        if (kt + 1 < ktiles) {
            #pragma unroll
            for (int i = 0; i < 4; i++)
                *(uint4*)&Ks[cur ^ 1][4 * g4 + i][dg * 8] = kq[i];
            STOREV_(cur ^ 1);
        }
        // ---- issue prefetch of tile kt+2 ----
        if (kt + 2 < ktiles) {
            size_t off = (size_t)(kt + 2) * 64 * 3072;
            #pragma unroll
            for (int i = 0; i < 4; i++) {
                kq[i] = *(const uint4*)(gkp + off + (size_t)i * 3072);
                vq[i] = *(const uint4*)(gvp + off + (size_t)i * 3072);
            }
        }
        // ---- S^T = K * Q^T : col=q=l, row=key=(r&3)+8(r>>2)+4hi (+32*c) ----
        floatx16 s0 = (floatx16)0.0f, s1 = (floatx16)0.0f;
        #pragma unroll
        for (int kk = 0; kk < 4; kk++) {
            short8 k0 = *(const short8*)&Ks[cur][l][kk * 16 + hi * 8];
            s0 = __builtin_amdgcn_mfma_f32_32x32x16_bf16(k0, qf[kk], s0, 0, 0, 0);
        }
        #pragma unroll
        for (int kk = 0; kk < 4; kk++) {
            short8 k1 = *(const short8*)&Ks[cur][32 + l][kk * 16 + hi * 8];
            s1 = __builtin_amdgcn_mfma_f32_32x32x16_bf16(k1, qf[kk], s1, 0, 0, 0);
        }
        // ---- causal mask: only the diagonal tile ----
        if (kt == strip) {
            int qg = q0w + l;
            int kbase = kt * 64 + 4 * hi;
            #pragma unroll
            for (int r = 0; r < 16; r++) {
                int key0 = kbase + (r & 3) + 8 * (r >> 2);
                if (key0 > qg) s0[r] = -1e30f;
                if (key0 + 32 > qg) s1[r] = -1e30f;
            }
        }
        // ---- online softmax in log2 space (q = l, per-lane scalar) ----
        float mx = s0[0];
        #pragma unroll
        for (int r = 1; r < 16; r++) mx = fmaxf(mx, s0[r]);
        #pragma unroll
        for (int r = 0; r < 16; r++) mx = fmaxf(mx, s1[r]);
        mx = fmaxf(mx, __shfl_xor(mx, 32));
        float mold = m_s;
        if (!__all(mx <= mold + 8.0f)) {   // T13 defer-max
            float mnew = fmaxf(mold, mx);
            float alpha = exp2v(mold - mnew);
            m_s = mnew;
            l_s *= alpha;
            #pragma unroll
            for (int r = 0; r < 16; r++) {
                acc_o[0][r] *= alpha;
                acc_o[1][r] *= alpha;
            }
        }
        float mcur = m_s;
        float p0[16], p1[16];
        float psum = 0.f;
        #pragma unroll
        for (int r = 0; r < 16; r++) { p0[r] = exp2v(s0[r] - mcur); psum += p0[r]; }
        #pragma unroll
        for (int r = 0; r < 16; r++) { p1[r] = exp2v(s1[r] - mcur); psum += p1[r]; }
        psum += __shfl_xor(psum, 32);
        l_s += psum;
        // ---- pack P -> 4 B-frags via cvt_pk + permlane32_swap (T12) ----
        short8 pf[4];
        #pragma unroll
        for (int c = 0; c < 2; c++) {
            #pragma unroll
            for (int half = 0; half < 2; half++) {
                const float* pp = c ? p1 : p0;
                uint32_t X = cvtpk(pp[half * 8 + 0], pp[half * 8 + 1]);
                uint32_t Y = cvtpk(pp[half * 8 + 2], pp[half * 8 + 3]);
                uint32_t Z = cvtpk(pp[half * 8 + 4], pp[half * 8 + 5]);
                uint32_t W = cvtpk(pp[half * 8 + 6], pp[half * 8 + 7]);
                // swap(vdst=X, vsrc=Z): hi=0 {X=(k0,k1),Z<-partnerX=(k4,k5)},
                // hi=1 {X<-partnerZ=(k8,k9), Z=(k12,k13)}; same for (Y,W).
                asm volatile("v_permlane32_swap_b32 %0, %1" : "+v"(X), "+v"(Z));
                asm volatile("v_permlane32_swap_b32 %0, %1" : "+v"(Y), "+v"(W));
                short8 f;
                ((uint32_t*)&f)[0] = X;
                ((uint32_t*)&f)[1] = Y;
                ((uint32_t*)&f)[2] = Z;
                ((uint32_t*)&f)[3] = W;
                pf[c * 2 + half] = f;
            }
        }
        // ---- O^T += V^T * P^T : col=q (per-lane), rows=d ----
        #pragma unroll
        for (int dt = 0; dt < 2; dt++) {
            int dd = dt * 32 + l;
            int cb = 2 * (dd >> 3);
            #pragma unroll
            for (int ks = 0; ks < 4; ks++) {
                int col = 4 * ((ks * 4 + hi * 2) ^ cb);
                short8 v = *(const short8*)&Vt[cur][dd][col];
                acc_o[dt] = __builtin_amdgcn_mfma_f32_32x32x16_bf16(
                    v, pf[ks], acc_o[dt], 0, 0, 0);
            }
        }
        __syncthreads();
    }
#undef STOREV_

    // ---- epilogue: per-lane scalar normalize, packed bf16 stores ----
    float inv = 1.0f / l_s;
    uint16_t* yp = y + (size_t)(b * T_ + q0w + l) * 1024 + h * 64;
    #pragma unroll
    for (int dt = 0; dt < 2; dt++) {
        #pragma unroll
        for (int rb = 0; rb < 4; rb++) {
            uint2 st;
            st.x = cvtpk(acc_o[dt][rb * 4 + 0] * inv, acc_o[dt][rb * 4 + 1] * inv);
            st.y = cvtpk(acc_o[dt][rb * 4 + 2] * inv, acc_o[dt][rb * 4 + 3] * inv);
            *(uint2*)(yp + dt * 32 + rb * 8 + hi * 4) = st;
        }
    }
}

extern "C" void kernel_launch(void* const* d_in, const int* in_sizes, int n_in,
                              void* d_out, int out_size, void* d_ws, size_t ws_size,
                              hipStream_t stream) {
    const float* x      = (const float*)d_in[0];  // [B,T,C] fp32
    const float* w_qkv  = (const float*)d_in[1];  // [C, 3HD] fp32
    const float* w_proj = (const float*)d_in[2];  // [HD, C] fp32
    const float* sink   = (const float*)d_in[3];  // [H] fp32
    float* out          = (float*)d_out;          // [B,T,C] fp32

    char* ws = (char*)d_ws;
    uint16_t* wt_qkv  = (uint16_t*)ws;                       // [3072,1024] 6.29 MB
    uint16_t* wt_proj = (uint16_t*)(ws + 6291456);           // [1024,1024] 2.10 MB
    uint16_t* x_c     = (uint16_t*)(ws + 8388608);           // [4096,1024] 8.39 MB
    uint16_t* qkv     = (uint16_t*)(ws + 16777216);          // [4096,3072] 25.17 MB
    uint16_t* yb      = (uint16_t*)(ws + 41943040);          // [4096,1024] 8.39 MB

    // fused prep: canon + both transposes in ONE dispatch
    prep<<<dim3(8192), 256, 0, stream>>>(x, x_c, w_qkv, wt_qkv, w_proj, wt_proj);

    // 1D grids, nwg % 8 == 0 (bijective XCD swizzle inside)
    gemm_bt<false, 128><<<dim3(768), 256, 0, stream>>>(
        x_c, wt_qkv, qkv, 4096, 3072, 1024);

    // strip-per-block grid: id = (31-strip)*32 + bh (longest first; id%8=bh%8)
    attn_mfma<<<dim3(32 * 32), 128, 0, stream>>>(qkv, sink, yb);

    // proj: 128x64 tiles -> 512 blocks = 2 blocks/CU
    gemm_bt<true, 64><<<dim3(512), 256, 0, stream>>>(
        yb, wt_proj, out, 4096, 1024, 1024);
}

// Round 10
// 177.699 us; speedup vs baseline: 1.2365x; 1.0980x over previous
//
#include <hip/hip_runtime.h>
#include <hip/hip_bf16.h>
#include <stdint.h>

#define B_ 2
#define T_ 2048
#define C_ 1024
#define H_ 16
#define D_ 64

typedef __attribute__((ext_vector_type(8))) short short8;
typedef __attribute__((ext_vector_type(4))) float floatx4;

__device__ __forceinline__ float bf2f(uint16_t b) {
    return __uint_as_float(((uint32_t)b) << 16);
}
__device__ __forceinline__ uint16_t f2b(float f) {
    __hip_bfloat16 h = __float2bfloat16(f);  // RNE
    return *(uint16_t*)&h;
}
// 2^x via v_exp_f32 (gfx9 transcendentals are HW-interlocked; reg-only asm)
__device__ __forceinline__ float exp2v(float x) {
    float r;
    asm("v_exp_f32 %0, %1" : "=v"(r) : "v"(x));
    return r;
}
// pack 2 f32 -> 2 bf16 (RNE), lo first
__device__ __forceinline__ uint32_t cvtpk(float lo, float hi) {
    uint32_t r;
    asm("v_cvt_pk_bf16_f32 %0, %1, %2" : "=v"(r) : "v"(lo), "v"(hi));
    return r;
}
__device__ __forceinline__ void glds16(const uint16_t* g, uint16_t* l) {
    __builtin_amdgcn_global_load_lds(
        (const __attribute__((address_space(1))) uint32_t*)g,
        (__attribute__((address_space(3))) uint32_t*)l, 16, 0, 0);
}

// ---- fused prep: canon x (fp32->bf16) + both weight transposes ------------
// blocks [0,4096): canon; [4096,4864): w_qkv transpose (64x64 tiles);
// [4864,5120): w_proj transpose. 64x64 tiles -> transposed writes are full
// 128B lines (old 32x32 wrote 64B half-lines).
__global__ void prep(const float* __restrict__ x, uint16_t* __restrict__ x_c,
                     const float* __restrict__ w_qkv, uint16_t* __restrict__ wt_qkv,
                     const float* __restrict__ w_proj, uint16_t* __restrict__ wt_proj) {
    __shared__ uint16_t tile[64][65];
    int id = blockIdx.x;
    int tid = threadIdx.x;
    if (id < 4096) {
        int i = (id * 256 + tid) * 4;
        float4 v = *(const float4*)(x + i);
        x_c[i + 0] = f2b(v.x);
        x_c[i + 1] = f2b(v.y);
        x_c[i + 2] = f2b(v.z);
        x_c[i + 3] = f2b(v.w);
        return;
    }
    const float* in;
    uint16_t* out;
    int R, W, bx, by;
    if (id < 4864) {
        int tb = id - 4096;
        in = w_qkv; out = wt_qkv; R = 1024; W = 3072;
        bx = tb % 48; by = tb / 48;
    } else {
        int tb = id - 4864;
        in = w_proj; out = wt_proj; R = 1024; W = 1024;
        bx = tb & 15; by = tb >> 4;
    }
    int tx = tid & 63, ty = tid >> 6;
    int c0 = bx * 64, r0 = by * 64;
    #pragma unroll
    for (int i = 0; i < 64; i += 4)
        tile[ty + i][tx] = f2b(in[(size_t)(r0 + ty + i) * W + (c0 + tx)]);
    __syncthreads();
    #pragma unroll
    for (int i = 0; i < 64; i += 4)
        out[(size_t)(c0 + ty + i) * R + (r0 + tx)] = tile[tx][ty + i];
}

// ------- GEMM: C[M,N] = A[M,K] @ Bt[N,K]^T ; bf16 in, fp32 acc -------------
// Counted-vmcnt pipeline (T3+T4): BK=32, THREE LDS buffers, depth-2
// global_load_lds prefetch; never drain vmcnt to 0 in the main loop (m218).
// XOR slot swizzle with pre-swizzled global source. Grid 1D, bijective XCD
// swizzle (nwg % 8 == 0), A-panel-major. No sched_barrier: the vmcnt asm's
// memory clobber already orders stage-issue; pinning can defeat the
// scheduler (m141).
template <bool OUT_F32, int BN>
__global__ __launch_bounds__(256, 3)
void gemm_bt(const uint16_t* __restrict__ A, const uint16_t* __restrict__ Bt,
             void* __restrict__ Cv, int M, int N, int K) {
    constexpr int NJ = BN / 32;           // per-wave 16-col frags
    constexpr int BUFB = BN * 32;         // u16 per B buffer
    __shared__ uint16_t As[3][128][32];
    __shared__ uint16_t Bs[3][BN][32];
    int tid = threadIdx.x;
    int w = tid >> 6, lane = tid & 63;
    int quad = lane >> 4, l16 = lane & 15;
    int wr = (w >> 1) * 64, wc = (w & 1) * (BN / 2);

    int nwg = gridDim.x;
    int wg = (blockIdx.x & 7) * (nwg >> 3) + (blockIdx.x >> 3);
    int nby = N / BN;
    int row0 = (wg / nby) * 128;
    int col0 = (wg % nby) * BN;

    int sr = w * 32 + (lane >> 2);
    int gscA = ((lane & 3) ^ ((lane >> 2) & 3)) * 8;
    uint16_t* lA0 = &As[0][sr][(lane & 3) * 8];
    const uint16_t* gA = A + (size_t)(row0 + sr) * K + gscA;
    int srB = (BN == 128) ? sr : (tid >> 2);
    int gscB = ((lane & 3) ^ (srB & 3)) * 8;
    uint16_t* lB0 = &Bs[0][srB][(lane & 3) * 8];
    const uint16_t* gB = Bt + (size_t)(col0 + srB) * K + gscB;

    floatx4 acc[4][NJ];
    #pragma unroll
    for (int i = 0; i < 4; i++)
        #pragma unroll
        for (int j = 0; j < NJ; j++)
            acc[i][j] = (floatx4){0.f, 0.f, 0.f, 0.f};

#define STAGE3_(bs_, t_)                                                    \
    {                                                                       \
        const uint16_t* ga_ = gA + (size_t)(t_) * 32;                       \
        const uint16_t* gb_ = gB + (size_t)(t_) * 32;                       \
        uint16_t* la_ = lA0 + (bs_) * 4096;                                 \
        uint16_t* lb_ = lB0 + (bs_) * BUFB;                                 \
        glds16(ga_, la_);                                                   \
        glds16(ga_ + 16 * K, la_ + 512);                                    \
        glds16(gb_, lb_);                                                   \
        if constexpr (BN == 128) glds16(gb_ + 16 * K, lb_ + 512);           \
    }

    int NT = K >> 5;                 // K=1024 -> 32 tiles
    STAGE3_(0, 0);
    STAGE3_(1, 1);
    if constexpr (BN == 128)
        asm volatile("s_waitcnt vmcnt(4)" ::: "memory");   // tile 0 resident
    else
        asm volatile("s_waitcnt vmcnt(3)" ::: "memory");
    __builtin_amdgcn_s_barrier();

    const uint16_t* Ab = &As[0][0][0];
    const uint16_t* Bb = &Bs[0][0][0];
    int s = (quad ^ (l16 & 3)) * 8;  // swizzled read slot (loop-invariant)
    int bc = 0, bs = 2;
    for (int t = 0; t < NT; ++t) {
        if (t + 2 < NT) STAGE3_(bs, t + 2);
        const uint16_t* Ac = Ab + bc * 4096;
        const uint16_t* Bc = Bb + bc * BUFB;
        short8 af[4], bfr[NJ];
        #pragma unroll
        for (int i = 0; i < 4; i++)
            af[i] = *(const short8*)&Ac[(wr + i * 16 + l16) * 32 + s];
        #pragma unroll
        for (int j = 0; j < NJ; j++)
            bfr[j] = *(const short8*)&Bc[(wc + j * 16 + l16) * 32 + s];
        #pragma unroll
        for (int i = 0; i < 4; i++)
            #pragma unroll
            for (int j = 0; j < NJ; j++)
                acc[i][j] = __builtin_amdgcn_mfma_f32_16x16x32_bf16(
                    af[i], bfr[j], acc[i][j], 0, 0, 0);
        if (t + 2 < NT) {
            if constexpr (BN == 128)
                asm volatile("s_waitcnt vmcnt(4)" ::: "memory");  // t+1 ready
            else
                asm volatile("s_waitcnt vmcnt(3)" ::: "memory");
        } else {
            asm volatile("s_waitcnt vmcnt(0)" ::: "memory");      // tail drain
        }
        __builtin_amdgcn_s_barrier();
        bc = (bc == 2) ? 0 : bc + 1;
        bs = (bs == 2) ? 0 : bs + 1;
    }
#undef STAGE3_

    #pragma unroll
    for (int i = 0; i < 4; i++) {
        #pragma unroll
        for (int j = 0; j < NJ; j++) {
            int rbase = row0 + wr + i * 16 + quad * 4;
            int cg = col0 + wc + j * 16 + l16;
            #pragma unroll
            for (int r = 0; r < 4; r++) {
                if (OUT_F32)
                    ((float*)Cv)[(size_t)(rbase + r) * N + cg] = acc[i][j][r];
                else
                    ((uint16_t*)Cv)[(size_t)(rbase + r) * N + cg] = f2b(acc[i][j][r]);
            }
        }
    }
}

// ---------------- MFMA flash attention with sink (round-6 version) ---------
// STRIP-PER-BLOCK: block (strip,bh), 1024 blocks (3 resident/CU, 46 KB LDS).
// 4 waves each own 16 q-rows of the strip and run identical code for
// strip+1 k-tiles -> perfect wave balance. Longest strips dispatch first;
// id%8 = bh%8 keeps same-head blocks on one XCD L2. log2-space softmax,
// defer-max (T13, THR=8), v_cvt_pk_bf16_f32 P-packing.
__global__ __launch_bounds__(256, 3)
void attn_mfma(const uint16_t* __restrict__ qkv,
               const float* __restrict__ sink,
               uint16_t* __restrict__ y) {
    __shared__ uint16_t Ks[2][64][72];   // [buf][key][d]   18432 B
    __shared__ uint16_t Vt[2][64][72];   // [buf][d][key]   18432 B (swizzled)
    __shared__ uint16_t Pl[4][16][72];   // per-wave [q][key] 9216 B

    int tid = threadIdx.x;
    int w = tid >> 6, lane = tid & 63;
    int quad = lane >> 4, l16 = lane & 15;

    int id = blockIdx.x;
    int strip = 31 - (id >> 5);         // longest first
    int bh = id & 31;
    int b = bh >> 4, h = bh & 15;
    int q0 = strip * 64 + w * 16;       // this wave's 16 q rows
    int ktiles = strip + 1;

    const uint16_t* qkv_b = qkv + (size_t)b * T_ * 3072;

    // ---- Q fragments: 2 kd, pre-scaled by log2(e)/8 ----
    const float QSC = 0.125f * 1.44269504f;
    short8 qf[2];
    {
        int qrow = q0 + l16;
        #pragma unroll
        for (int kd = 0; kd < 2; kd++) {
            uint4 raw = *(const uint4*)(qkv_b + (size_t)qrow * 3072 + h * 64 +
                                        kd * 32 + quad * 8);
            const uint16_t* rp = (const uint16_t*)&raw;
            short8 f;
            #pragma unroll
            for (int j = 0; j < 8; j++)
                f[j] = (short)f2b(bf2f(rp[j]) * QSC);
            qf[kd] = f;
        }
    }

    float m_s = sink[h] * 1.44269504f;   // log2 space
    float l_s = 1.0f;
    floatx4 acc_o[4];
    #pragma unroll
    for (int dt = 0; dt < 4; dt++)
        acc_o[dt] = (floatx4){0.f, 0.f, 0.f, 0.f};

    // ---- staging map: thread (t2,dg): key rows 2t2,2t2+1, dims dg*8..+7 ----
    int t2 = tid >> 3;
    int dg = tid & 7;
    const uint16_t* kgp = qkv_b + 1024 + h * 64 + (size_t)(2 * t2) * 3072 + dg * 8;
    const uint16_t* vgp = kgp + 1024;
    int vcw = 2 * (t2 ^ (4 * dg));   // swizzled u16 col for V^T key-pair store

    uint4 kr0 = *(const uint4*)(kgp);
    uint4 kr1 = *(const uint4*)(kgp + 3072);
    uint4 vr0 = *(const uint4*)(vgp);
    uint4 vr1 = *(const uint4*)(vgp + 3072);
    // store tile 0 -> buf 0
    {
        *(uint4*)&Ks[0][2 * t2][dg * 8] = kr0;
        *(uint4*)&Ks[0][2 * t2 + 1][dg * 8] = kr1;
        const uint16_t* a0 = (const uint16_t*)&vr0;
        const uint16_t* a1 = (const uint16_t*)&vr1;
        #pragma unroll
        for (int j = 0; j < 8; j++)
            *(uint32_t*)&Vt[0][dg * 8 + j][vcw] =
                (uint32_t)a0[j] | ((uint32_t)a1[j] << 16);
    }
    if (ktiles > 1) {   // preload tile 1
        kr0 = *(const uint4*)(kgp + 64 * 3072);
        kr1 = *(const uint4*)(kgp + 64 * 3072 + 3072);
        vr0 = *(const uint4*)(vgp + 64 * 3072);
        vr1 = *(const uint4*)(vgp + 64 * 3072 + 3072);
    }
    __syncthreads();

    for (int kt = 0; kt < ktiles; kt++) {
        int cur = kt & 1;
        // ---- store prefetched tile kt+1 into the other buffer ----
        if (kt + 1 < ktiles) {
            *(uint4*)&Ks[cur ^ 1][2 * t2][dg * 8] = kr0;
            *(uint4*)&Ks[cur ^ 1][2 * t2 + 1][dg * 8] = kr1;
            const uint16_t* a0 = (const uint16_t*)&vr0;
            const uint16_t* a1 = (const uint16_t*)&vr1;
            #pragma unroll
            for (int j = 0; j < 8; j++)
                *(uint32_t*)&Vt[cur ^ 1][dg * 8 + j][vcw] =
                    (uint32_t)a0[j] | ((uint32_t)a1[j] << 16);
        }
        // ---- issue prefetch of tile kt+2 (lands during this iter) ----
        if (kt + 2 < ktiles) {
            size_t off = (size_t)(kt + 2) * 64 * 3072;
            kr0 = *(const uint4*)(kgp + off);
            kr1 = *(const uint4*)(kgp + off + 3072);
            vr0 = *(const uint4*)(vgp + off);
            vr1 = *(const uint4*)(vgp + off + 3072);
        }
        // ---- K and V fragments ----
        short8 kf[4][2];
        #pragma unroll
        for (int rt = 0; rt < 4; rt++) {
            kf[rt][0] = *(const short8*)&Ks[cur][rt * 16 + l16][quad * 8];
            kf[rt][1] = *(const short8*)&Ks[cur][rt * 16 + l16][32 + quad * 8];
        }
        short8 vf[2][4];
        #pragma unroll
        for (int kb = 0; kb < 2; kb++)
            #pragma unroll
            for (int dt = 0; dt < 4; dt++) {
                int d = dt * 16 + l16;
                int col = 2 * (((kb * 16) + quad * 4) ^ (4 * (d >> 3)));
                vf[kb][dt] = *(const short8*)&Vt[cur][d][col];
            }
        // ---- S^T = K * Q^T : key = rt*16+quad*4+r, q = l16 ----
        floatx4 acc_s[4];
        #pragma unroll
        for (int rt = 0; rt < 4; rt++)
            acc_s[rt] = (floatx4){0.f, 0.f, 0.f, 0.f};
        #pragma unroll
        for (int rt = 0; rt < 4; rt++) {
            acc_s[rt] = __builtin_amdgcn_mfma_f32_16x16x32_bf16(
                kf[rt][0], qf[0], acc_s[rt], 0, 0, 0);
            acc_s[rt] = __builtin_amdgcn_mfma_f32_16x16x32_bf16(
                kf[rt][1], qf[1], acc_s[rt], 0, 0, 0);
        }
        // ---- causal mask: only the diagonal tile ----
        if (kt == strip) {
            int qg = q0 + l16;
            #pragma unroll
            for (int rt = 0; rt < 4; rt++) {
                int kg = kt * 64 + rt * 16 + quad * 4;
                #pragma unroll
                for (int r = 0; r < 4; r++)
                    if (kg + r > qg) acc_s[rt][r] = -1e30f;
            }
        }
        // ---- online softmax in log2 space (q = l16) ----
        float mx = -1e30f;
        #pragma unroll
        for (int rt = 0; rt < 4; rt++)
            #pragma unroll
            for (int r = 0; r < 4; r++) mx = fmaxf(mx, acc_s[rt][r]);
        mx = fmaxf(mx, __shfl_xor(mx, 16));
        mx = fmaxf(mx, __shfl_xor(mx, 32));
        float mold = m_s;
        // T13 defer-max: only rescale when tile max exceeds m by >8
        if (!__all(mx <= mold + 8.0f)) {
            float mnew = fmaxf(mold, mx);
            float alpha = exp2v(mold - mnew);
            m_s = mnew;
            l_s *= alpha;
            #pragma unroll
            for (int r = 0; r < 4; r++) {
                float ar = __shfl(alpha, (lane & 48) | (quad * 4 + r));
                #pragma unroll
                for (int dt = 0; dt < 4; dt++) acc_o[dt][r] *= ar;
            }
        }
        float mcur = m_s;
        float psum = 0.f;
        #pragma unroll
        for (int rt = 0; rt < 4; rt++) {
            float p0 = exp2v(acc_s[rt][0] - mcur);
            float p1 = exp2v(acc_s[rt][1] - mcur);
            float p2 = exp2v(acc_s[rt][2] - mcur);
            float p3 = exp2v(acc_s[rt][3] - mcur);
            psum += (p0 + p1) + (p2 + p3);
            uint2 pk;
            pk.x = cvtpk(p0, p1);
            pk.y = cvtpk(p2, p3);
            *(uint2*)&Pl[w][l16][rt * 16 + quad * 4] = pk;
        }
        psum += __shfl_xor(psum, 16);
        psum += __shfl_xor(psum, 32);
        l_s += psum;
        // ---- O += P * V ----
        #pragma unroll
        for (int kb = 0; kb < 2; kb++) {
            short8 pf = *(const short8*)&Pl[w][l16][kb * 32 + quad * 8];
            #pragma unroll
            for (int dt = 0; dt < 4; dt++)
                acc_o[dt] = __builtin_amdgcn_mfma_f32_16x16x32_bf16(
                    pf, vf[kb][dt], acc_o[dt], 0, 0, 0);
        }
        __syncthreads();
    }

    // ---- epilogue: normalize by l (per-q via in-quad shuffle), store bf16 --
    #pragma unroll
    for (int r = 0; r < 4; r++) {
        float lr = __shfl(l_s, (lane & 48) | (quad * 4 + r));
        float inv = 1.0f / lr;
        int qg = q0 + quad * 4 + r;
        uint16_t* yp = y + (size_t)(b * T_ + qg) * 1024 + h * 64;
        #pragma unroll
        for (int dt = 0; dt < 4; dt++)
            yp[dt * 16 + l16] = f2b(acc_o[dt][r] * inv);
    }
}

extern "C" void kernel_launch(void* const* d_in, const int* in_sizes, int n_in,
                              void* d_out, int out_size, void* d_ws, size_t ws_size,
                              hipStream_t stream) {
    const float* x      = (const float*)d_in[0];  // [B,T,C] fp32
    const float* w_qkv  = (const float*)d_in[1];  // [C, 3HD] fp32
    const float* w_proj = (const float*)d_in[2];  // [HD, C] fp32
    const float* sink   = (const float*)d_in[3];  // [H] fp32
    float* out          = (float*)d_out;          // [B,T,C] fp32

    char* ws = (char*)d_ws;
    uint16_t* wt_qkv  = (uint16_t*)ws;                       // [3072,1024] 6.29 MB
    uint16_t* wt_proj = (uint16_t*)(ws + 6291456);           // [1024,1024] 2.10 MB
    uint16_t* x_c     = (uint16_t*)(ws + 8388608);           // [4096,1024] 8.39 MB
    uint16_t* qkv     = (uint16_t*)(ws + 16777216);          // [4096,3072] 25.17 MB
    uint16_t* yb      = (uint16_t*)(ws + 41943040);          // [4096,1024] 8.39 MB

    // fused prep: canon + both transposes (64x64 tiles) in ONE dispatch
    prep<<<dim3(5120), 256, 0, stream>>>(x, x_c, w_qkv, wt_qkv, w_proj, wt_proj);

    // 1D grids, nwg % 8 == 0 (bijective XCD swizzle inside)
    gemm_bt<false, 128><<<dim3(768), 256, 0, stream>>>(
        x_c, wt_qkv, qkv, 4096, 3072, 1024);

    // strip-per-block grid: id = (31-strip)*32 + bh (longest first; id%8=bh%8)
    attn_mfma<<<dim3(32 * 32), 256, 0, stream>>>(qkv, sink, yb);

    // proj: 128x64 tiles -> 512 blocks = 2 blocks/CU
    gemm_bt<true, 64><<<dim3(512), 256, 0, stream>>>(
        yb, wt_proj, out, 4096, 1024, 1024);
}